// Round 9
// baseline (83.849 us; speedup 1.0000x reference)
//
#include <hip/hip_runtime.h>

// Cost volume loss: pred/target (8,3,512,512) f32.
// Per pixel: min over 5x5 offsets (zero-padded target) of mean_C |pred - patch|,
// then global mean. Output: single f32 scalar.
//
// Thread = 4 cols x 2 rows (8 px). Block = 512 cols x 4 rows. Grid = 1024 blocks.
// Block-level edge specialization: 126/128 h-groups take an EDGE=false path with
// NO runtime branches in the row loop (straight-line loads -> scheduler can
// software-pipeline); only hg==0/127 blocks run the branched edge path.
// Single compute dispatch: blocks atomicAdd scaled partials into d_out[0]
// (zeroed by a 4-byte async memset). No final kernel.

#define H_DIM 512
#define W_DIM 512
#define N_DIM 8
#define C_DIM 3
#define HW (H_DIM * W_DIM)
#define CHW (C_DIM * HW)
#define NPIX (N_DIM * HW)
#define NBLOCKS 1024
#define BIGF 3.0e38f

typedef float f4 __attribute__((ext_vector_type(4)));

template <bool EDGE>
__device__ __forceinline__ float thread_partial(const float* __restrict__ pred,
                                                const float* __restrict__ targ,
                                                size_t nbase, int h0, int w0,
                                                int col) {
    // ---- pred: 2 rows x 3 channels x 4 px ----
    f4 pv[2][3];
#pragma unroll
    for (int r = 0; r < 2; ++r)
#pragma unroll
        for (int c = 0; c < 3; ++c)
            pv[r][c] = *(const f4*)(pred + nbase + (size_t)c * HW +
                                    (size_t)(h0 + r) * W_DIM + w0);

    const bool wlo = (col == 0);          // w0 == 0
    const bool whi = (col == 127);        // w0 == 508
    const int am = wlo ? 0 : (w0 - 2);            // left window load col
    const int bp = whi ? (W_DIM - 4) : (w0 + 2);  // right window load col
    const float* trow = targ + nbase;

    // ---- seed best: border pixels get the zero-pad candidate sum|pred| ----
    float best[2][4];
#pragma unroll
    for (int r = 0; r < 2; ++r) {
        bool hcand = false;
        if (EDGE) {
            const int hp = h0 + r;
            hcand = (hp < 2) || (hp >= H_DIM - 2);
        }
#pragma unroll
        for (int px = 0; px < 4; ++px) {
            const bool wcand = (px < 2) ? wlo : whi;
            const float soob =
                fabsf(pv[r][0][px]) + fabsf(pv[r][1][px]) + fabsf(pv[r][2][px]);
            best[r][px] = (hcand || wcand) ? soob : BIGF;
        }
    }

    // ---- 6 target rows; EDGE=false instantiation is branch-free ----
#pragma unroll
    for (int j = 0; j < 6; ++j) {
        const int hh = h0 - 2 + j;
        const bool rowok = !EDGE || (hh >= 0 && hh < H_DIM);  // wave-uniform
        if (rowok) {
            // 8-float window per channel: cols [w0-2, w0+6)
            float w[3][8];
#pragma unroll
            for (int c = 0; c < 3; ++c) {
                const float* rowp = trow + (size_t)c * HW + (size_t)hh * W_DIM;
                const f4 a = *(const f4*)(rowp + am);
                const f4 b = *(const f4*)(rowp + bp);
                w[c][0] = a[0];
                w[c][1] = a[1];
                w[c][2] = wlo ? a[0] : a[2];   // col 0 at left edge
                w[c][3] = wlo ? a[1] : a[3];   // col 1 at left edge
                w[c][4] = whi ? b[2] : b[0];   // col 510 at right edge
                w[c][5] = whi ? b[3] : b[1];   // col 511 at right edge
                w[c][6] = b[2];
                w[c][7] = b[3];
            }
#pragma unroll
            for (int r = 0; r < 2; ++r) {
                const int di = j - 2 - r;          // compile-time after unroll
                if (di >= -2 && di <= 2) {
#pragma unroll
                    for (int px = 0; px < 4; ++px) {
#pragma unroll
                        for (int dj = -2; dj <= 2; ++dj) {
                            const int ix = px + dj + 2;  // 0..7
                            float s = fabsf(pv[r][0][px] - w[0][ix])
                                    + fabsf(pv[r][1][px] - w[1][ix])
                                    + fabsf(pv[r][2][px] - w[2][ix]);
                            // out-of-image candidates invalid at w edges:
                            if (px + dj < 0)      s = wlo ? BIGF : s;
                            else if (px + dj > 3) s = whi ? BIGF : s;
                            best[r][px] = fminf(best[r][px], s);
                        }
                    }
                }
            }
        }
        // EDGE && !rowok: zero-pad candidate already seeded into best.
    }

    float v = 0.0f;
#pragma unroll
    for (int r = 0; r < 2; ++r)
#pragma unroll
        for (int px = 0; px < 4; ++px)
            v += best[r][px];
    return v;
}

__global__ __launch_bounds__(256, 4) void cvl_main(const float* __restrict__ pred,
                                                   const float* __restrict__ targ,
                                                   float* __restrict__ out) {
    const int tid = threadIdx.x;
    const int col = tid & 127;        // 0..127
    const int rg  = tid >> 7;         // 0..1 (wave-uniform)
    const int bid = blockIdx.x;       // 0..1023
    const int n   = bid >> 7;         // 0..7
    const int hg  = bid & 127;        // 0..127
    const int h0  = hg * 4 + rg * 2;  // first of this thread's 2 rows
    const int w0  = col * 4;          // first of this thread's 4 cols
    const size_t nbase = (size_t)n * CHW;

    float v;
    if (hg != 0 && hg != 127) {
        v = thread_partial<false>(pred, targ, nbase, h0, w0, col);  // branch-free
    } else {
        v = thread_partial<true>(pred, targ, nbase, h0, w0, col);
    }

    // ---- block reduce: wave shuffle, LDS, one scaled atomic per block ----
#pragma unroll
    for (int o = 32; o > 0; o >>= 1) v += __shfl_down(v, o, 64);

    __shared__ float ws[4];
    const int lane = tid & 63;
    const int wv   = tid >> 6;
    if (lane == 0) ws[wv] = v;
    __syncthreads();
    if (tid == 0) {
        const float bs = ws[0] + ws[1] + ws[2] + ws[3];
        atomicAdd(out, bs * (1.0f / (3.0f * (float)NPIX)));
    }
}

extern "C" void kernel_launch(void* const* d_in, const int* in_sizes, int n_in,
                              void* d_out, int out_size, void* d_ws, size_t ws_size,
                              hipStream_t stream) {
    const float* pred = (const float*)d_in[0];
    const float* targ = (const float*)d_in[1];
    float* out = (float*)d_out;

    hipMemsetAsync(out, 0, sizeof(float), stream);
    cvl_main<<<NBLOCKS, 256, 0, stream>>>(pred, targ, out);
}

// Round 10
// 23.330 us; speedup vs baseline: 3.5940x; 3.5940x over previous
//
#include <hip/hip_runtime.h>

// Cost volume loss: pred/target (8,3,512,512) f32.
// Per pixel: min over 5x5 offsets (zero-padded target) of mean_C |pred - patch|,
// then global mean. Output: single f32 scalar.
//
// Thread = 4 cols x 2 rows (8 px). Block = 512 cols x 4 rows. Grid = 1024 blocks.
// BRANCH-FREE row loop: row addresses are clamped to [0,511] so all 36 target
// loads issue unconditionally (scheduler can pipeline loads under compute);
// row validity is applied as ONE wave-uniform cndmask per (j,r,px) after the
// dj-min (clamped-row data must not beat best). Border pixels seed best with
// the zero-pad candidate sum|pred|. No templates (r9's duplication spilled).

#define H_DIM 512
#define W_DIM 512
#define N_DIM 8
#define C_DIM 3
#define HW (H_DIM * W_DIM)
#define CHW (C_DIM * HW)
#define NPIX (N_DIM * HW)
#define NBLOCKS 1024
#define BIGF 3.0e38f

typedef float f4 __attribute__((ext_vector_type(4)));

__global__ __launch_bounds__(256, 4) void cvl_main(const float* __restrict__ pred,
                                                   const float* __restrict__ targ,
                                                   float* __restrict__ partial) {
    const int tid = threadIdx.x;
    const int col = tid & 127;        // 0..127
    const int rg  = tid >> 7;         // 0..1 (wave-uniform)
    const int bid = blockIdx.x;       // 0..1023
    const int n   = bid >> 7;         // 0..7
    const int hg  = bid & 127;        // 0..127
    const int h0  = hg * 4 + rg * 2;  // first of this thread's 2 rows (wave-uniform)
    const int w0  = col * 4;          // first of this thread's 4 cols

    const size_t nbase = (size_t)n * CHW;

    // ---- pred: 2 rows x 3 channels x 4 px, nontemporal (streamed once) ----
    f4 pv[2][3];
#pragma unroll
    for (int r = 0; r < 2; ++r)
#pragma unroll
        for (int c = 0; c < 3; ++c)
            pv[r][c] = __builtin_nontemporal_load(
                (const f4*)(pred + nbase + (size_t)c * HW +
                            (size_t)(h0 + r) * W_DIM + w0));

    const bool wlo = (col == 0);          // w0 == 0
    const bool whi = (col == 127);        // w0 == 508
    const int am = wlo ? 0 : (w0 - 2);            // left window load col
    const int bp = whi ? (W_DIM - 4) : (w0 + 2);  // right window load col
    const float* trow = targ + nbase;

    // ---- seed best: border pixels get the zero-pad candidate sum|pred| ----
    float best[2][4];
#pragma unroll
    for (int r = 0; r < 2; ++r) {
        const int hp = h0 + r;
        const bool hcand = (hp < 2) || (hp >= H_DIM - 2);
#pragma unroll
        for (int px = 0; px < 4; ++px) {
            const bool wcand = (px < 2) ? wlo : whi;
            const float soob =
                fabsf(pv[r][0][px]) + fabsf(pv[r][1][px]) + fabsf(pv[r][2][px]);
            best[r][px] = (hcand || wcand) ? soob : BIGF;
        }
    }

    // ---- 6 target rows, fully branch-free (clamped addresses) ----
#pragma unroll
    for (int j = 0; j < 6; ++j) {
        const int hh = h0 - 2 + j;                       // wave-uniform
        const bool rowok = (hh >= 0) && (hh < H_DIM);    // wave-uniform
        const int hc = (hh < 0) ? 0 : ((hh >= H_DIM) ? (H_DIM - 1) : hh);

        // 8-float window per channel: cols [w0-2, w0+6), unconditional loads
        float w[3][8];
#pragma unroll
        for (int c = 0; c < 3; ++c) {
            const float* rowp = trow + (size_t)c * HW + (size_t)hc * W_DIM;
            const f4 a = *(const f4*)(rowp + am);
            const f4 b = *(const f4*)(rowp + bp);
            w[c][0] = a[0];
            w[c][1] = a[1];
            w[c][2] = wlo ? a[0] : a[2];   // col 0 at left edge
            w[c][3] = wlo ? a[1] : a[3];   // col 1 at left edge
            w[c][4] = whi ? b[2] : b[0];   // col 510 at right edge
            w[c][5] = whi ? b[3] : b[1];   // col 511 at right edge
            w[c][6] = b[2];
            w[c][7] = b[3];
        }

#pragma unroll
        for (int r = 0; r < 2; ++r) {
            const int di = j - 2 - r;          // compile-time after unroll
            if (di >= -2 && di <= 2) {
#pragma unroll
                for (int px = 0; px < 4; ++px) {
                    float rm = BIGF;           // min over dj for this row
#pragma unroll
                    for (int dj = -2; dj <= 2; ++dj) {
                        const int ix = px + dj + 2;  // 0..7
                        float s = fabsf(pv[r][0][px] - w[0][ix])
                                + fabsf(pv[r][1][px] - w[1][ix])
                                + fabsf(pv[r][2][px] - w[2][ix]);
                        // out-of-image candidates invalid at w edges:
                        if (px + dj < 0)      s = wlo ? BIGF : s;
                        else if (px + dj > 3) s = whi ? BIGF : s;
                        rm = fminf(rm, s);
                    }
                    // suppress clamped (out-of-image) rows — wave-uniform select:
                    best[r][px] = fminf(best[r][px], rowok ? rm : BIGF);
                }
            }
        }
    }

    // ---- block reduce: 8 px -> thread, wave shuffle, LDS, one store ----
    float v = 0.0f;
#pragma unroll
    for (int r = 0; r < 2; ++r)
#pragma unroll
        for (int px = 0; px < 4; ++px)
            v += best[r][px];

#pragma unroll
    for (int o = 32; o > 0; o >>= 1) v += __shfl_down(v, o, 64);

    __shared__ float ws[4];
    const int lane = tid & 63;
    const int wv   = tid >> 6;
    if (lane == 0) ws[wv] = v;
    __syncthreads();
    if (tid == 0) partial[bid] = ws[0] + ws[1] + ws[2] + ws[3];
}

__global__ __launch_bounds__(256) void cvl_final(const float* __restrict__ partial,
                                                 float* __restrict__ out) {
    const int tid = threadIdx.x;
    double v = 0.0;
#pragma unroll
    for (int k = 0; k < 4; ++k) v += (double)partial[tid + k * 256];
#pragma unroll
    for (int o = 32; o > 0; o >>= 1) v += __shfl_down(v, o, 64);

    __shared__ double ws[4];
    const int lane = tid & 63;
    const int wid  = tid >> 6;
    if (lane == 0) ws[wid] = v;
    __syncthreads();
    if (tid == 0) {
        const double s = ws[0] + ws[1] + ws[2] + ws[3];
        out[0] = (float)(s / (3.0 * (double)NPIX));
    }
}

extern "C" void kernel_launch(void* const* d_in, const int* in_sizes, int n_in,
                              void* d_out, int out_size, void* d_ws, size_t ws_size,
                              hipStream_t stream) {
    const float* pred = (const float*)d_in[0];
    const float* targ = (const float*)d_in[1];
    float* out = (float*)d_out;
    float* partial = (float*)d_ws;

    cvl_main<<<NBLOCKS, 256, 0, stream>>>(pred, targ, partial);
    cvl_final<<<1, 256, 0, stream>>>(partial, out);
}

// Round 11
// 19.088 us; speedup vs baseline: 4.3927x; 1.2222x over previous
//
#include <hip/hip_runtime.h>

// Cost volume loss: pred/target (8,3,512,512) f32.
// Per pixel: min over 5x5 offsets (zero-padded target) of mean_C |pred - patch|,
// then global mean. Output: single f32 scalar.
//
// VMEM-issue-bound hypothesis (r3/r8/r10 all = 5.25 loads/px = 22-23us; r1 =
// 78 loads/px = 112us). This round: 3.75 loads/px.
// Thread = 4 cols x 4 rows (16 px): 8 target rows x 3ch x 2 f4-windows + 12
// pred = 60 loads/thread. Block = 512 cols x 8 rows; grid = 512 blocks.
// Branch-free row loop via clamped row addresses + wave-uniform validity
// select (r10 machinery). Border pixels seed best with zero-pad candidate.

#define H_DIM 512
#define W_DIM 512
#define N_DIM 8
#define C_DIM 3
#define HW (H_DIM * W_DIM)
#define CHW (C_DIM * HW)
#define NPIX (N_DIM * HW)
#define NBLOCKS 512
#define BIGF 3.0e38f

typedef float f4 __attribute__((ext_vector_type(4)));

__global__ __launch_bounds__(256, 2) void cvl_main(const float* __restrict__ pred,
                                                   const float* __restrict__ targ,
                                                   float* __restrict__ partial) {
    const int tid = threadIdx.x;
    const int col = tid & 127;        // 0..127
    const int rg  = tid >> 7;         // 0..1 (wave-uniform)
    const int bid = blockIdx.x;       // 0..511
    const int n   = bid >> 6;         // 0..7
    const int hg  = bid & 63;         // 0..63
    const int h0  = hg * 8 + rg * 4;  // first of this thread's 4 rows (wave-uniform)
    const int w0  = col * 4;          // first of this thread's 4 cols

    const size_t nbase = (size_t)n * CHW;

    // ---- pred: 4 rows x 3 channels x 4 px, nontemporal (streamed once) ----
    f4 pv[4][3];
#pragma unroll
    for (int r = 0; r < 4; ++r)
#pragma unroll
        for (int c = 0; c < 3; ++c)
            pv[r][c] = __builtin_nontemporal_load(
                (const f4*)(pred + nbase + (size_t)c * HW +
                            (size_t)(h0 + r) * W_DIM + w0));

    const bool wlo = (col == 0);          // w0 == 0
    const bool whi = (col == 127);        // w0 == 508
    const int am = wlo ? 0 : (w0 - 2);            // left window load col
    const int bp = whi ? (W_DIM - 4) : (w0 + 2);  // right window load col
    const float* trow = targ + nbase;

    // ---- seed best: border pixels get the zero-pad candidate sum|pred| ----
    float best[4][4];
#pragma unroll
    for (int r = 0; r < 4; ++r) {
        const int hp = h0 + r;
        const bool hcand = (hp < 2) || (hp >= H_DIM - 2);
#pragma unroll
        for (int px = 0; px < 4; ++px) {
            const bool wcand = (px < 2) ? wlo : whi;
            const float soob =
                fabsf(pv[r][0][px]) + fabsf(pv[r][1][px]) + fabsf(pv[r][2][px]);
            best[r][px] = (hcand || wcand) ? soob : BIGF;
        }
    }

    // ---- 8 target rows, branch-free (clamped addresses) ----
#pragma unroll
    for (int j = 0; j < 8; ++j) {
        const int hh = h0 - 2 + j;                       // wave-uniform
        const bool rowok = (hh >= 0) && (hh < H_DIM);    // wave-uniform
        const int hc = (hh < 0) ? 0 : ((hh >= H_DIM) ? (H_DIM - 1) : hh);

        // 8-float window per channel: cols [w0-2, w0+6), unconditional loads
        float w[3][8];
#pragma unroll
        for (int c = 0; c < 3; ++c) {
            const float* rowp = trow + (size_t)c * HW + (size_t)hc * W_DIM;
            const f4 a = *(const f4*)(rowp + am);
            const f4 b = *(const f4*)(rowp + bp);
            w[c][0] = a[0];
            w[c][1] = a[1];
            w[c][2] = wlo ? a[0] : a[2];   // col 0 at left edge
            w[c][3] = wlo ? a[1] : a[3];   // col 1 at left edge
            w[c][4] = whi ? b[2] : b[0];   // col 510 at right edge
            w[c][5] = whi ? b[3] : b[1];   // col 511 at right edge
            w[c][6] = b[2];
            w[c][7] = b[3];
        }

#pragma unroll
        for (int r = 0; r < 4; ++r) {
            const int di = j - 2 - r;          // compile-time after unroll
            if (di >= -2 && di <= 2) {
#pragma unroll
                for (int px = 0; px < 4; ++px) {
                    float rm = BIGF;           // min over dj for this row
#pragma unroll
                    for (int dj = -2; dj <= 2; ++dj) {
                        const int ix = px + dj + 2;  // 0..7
                        float s = fabsf(pv[r][0][px] - w[0][ix])
                                + fabsf(pv[r][1][px] - w[1][ix])
                                + fabsf(pv[r][2][px] - w[2][ix]);
                        // out-of-image candidates invalid at w edges:
                        if (px + dj < 0)      s = wlo ? BIGF : s;
                        else if (px + dj > 3) s = whi ? BIGF : s;
                        rm = fminf(rm, s);
                    }
                    // suppress clamped (out-of-image) rows — wave-uniform:
                    best[r][px] = fminf(best[r][px], rowok ? rm : BIGF);
                }
            }
        }
    }

    // ---- block reduce: 16 px -> thread, wave shuffle, LDS, one store ----
    float v = 0.0f;
#pragma unroll
    for (int r = 0; r < 4; ++r)
#pragma unroll
        for (int px = 0; px < 4; ++px)
            v += best[r][px];

#pragma unroll
    for (int o = 32; o > 0; o >>= 1) v += __shfl_down(v, o, 64);

    __shared__ float ws[4];
    const int lane = tid & 63;
    const int wv   = tid >> 6;
    if (lane == 0) ws[wv] = v;
    __syncthreads();
    if (tid == 0) partial[bid] = ws[0] + ws[1] + ws[2] + ws[3];
}

__global__ __launch_bounds__(256) void cvl_final(const float* __restrict__ partial,
                                                 float* __restrict__ out) {
    const int tid = threadIdx.x;
    double v = (double)partial[tid] + (double)partial[tid + 256];
#pragma unroll
    for (int o = 32; o > 0; o >>= 1) v += __shfl_down(v, o, 64);

    __shared__ double ws[4];
    const int lane = tid & 63;
    const int wid  = tid >> 6;
    if (lane == 0) ws[wid] = v;
    __syncthreads();
    if (tid == 0) {
        const double s = ws[0] + ws[1] + ws[2] + ws[3];
        out[0] = (float)(s / (3.0 * (double)NPIX));
    }
}

extern "C" void kernel_launch(void* const* d_in, const int* in_sizes, int n_in,
                              void* d_out, int out_size, void* d_ws, size_t ws_size,
                              hipStream_t stream) {
    const float* pred = (const float*)d_in[0];
    const float* targ = (const float*)d_in[1];
    float* out = (float*)d_out;
    float* partial = (float*)d_ws;

    cvl_main<<<NBLOCKS, 256, 0, stream>>>(pred, targ, partial);
    cvl_final<<<1, 256, 0, stream>>>(partial, out);
}